// Round 10
// baseline (490.306 us; speedup 1.0000x reference)
//
#include <hip/hip_runtime.h>

#define H 64
#define BNODE_SHIFT 8           // 256 nodes per bucket
#define BNODES 256
#define CHUNK 4096              // edges per sort block (16 per thread)
#define EPT 16

// bf16 helpers: bf16->fp32 is exact (bit shift); fp32->bf16 round-to-nearest-even
static __device__ __forceinline__ float b2f(ushort b) {
    return __uint_as_float(((unsigned int)b) << 16);
}
static __device__ __forceinline__ ushort f2b(float f) {
    unsigned int u = __float_as_uint(f);
    return (ushort)((u + 0x7FFF + ((u >> 16) & 1)) >> 16);
}
#define RFL(x) __builtin_amdgcn_readfirstlane(x)

// ---------------- zero-fill ----------------
__global__ void zero_i32(int* p, int n) {
    int i = blockIdx.x * blockDim.x + threadIdx.x;
    if (i < n) p[i] = 0;
}

// ---------------- bucket histogram (LDS-local then merge) ----------------
__global__ void bucket_hist(const int* __restrict__ dst, int E,
                            int* __restrict__ bcounts, int nbuck) {
    __shared__ int hist[512];
    for (int i = threadIdx.x; i < nbuck; i += blockDim.x) hist[i] = 0;
    __syncthreads();
    for (int e = blockIdx.x * blockDim.x + threadIdx.x; e < E; e += gridDim.x * blockDim.x)
        atomicAdd(&hist[dst[e] >> BNODE_SHIFT], 1);
    __syncthreads();
    for (int i = threadIdx.x; i < nbuck; i += blockDim.x) {
        int v = hist[i];
        if (v) atomicAdd(&bcounts[i], v);
    }
}

// ---------------- bucket offsets scan (1 block) ----------------
__global__ void bucket_scan(const int* __restrict__ bcounts, int* __restrict__ boff,
                            int* __restrict__ bcur, int* __restrict__ rowstart,
                            int nbuck, int E, int N) {
    __shared__ int t[1024];
    int tid = threadIdx.x;
    int v = (tid < nbuck) ? bcounts[tid] : 0;
    t[tid] = v;
    __syncthreads();
    for (int off = 1; off < 1024; off <<= 1) {
        int x = (tid >= off) ? t[tid - off] : 0;
        __syncthreads();
        t[tid] += x;
        __syncthreads();
    }
    if (tid < nbuck) {
        int o = t[tid] - v;       // exclusive
        boff[tid] = o;
        bcur[tid * 16] = o;       // 64B-padded cursor
    }
    if (tid == 0) { boff[nbuck] = E; rowstart[N] = E; }
}

// ---------------- block-local LDS sort + fully parallel flush ----------------
// pack: src (bits 0..19) | local_dst (bits 20..27)
__global__ void edge_sort_scatter(const int* __restrict__ src, const int* __restrict__ dst,
                                  int E, int nbuck,
                                  int* __restrict__ bcur, int* __restrict__ pairs4) {
    __shared__ int hist[392];
    __shared__ int bstart[393];
    __shared__ int cur[392];
    __shared__ int gbase[392];
    __shared__ int wsum[256];
    __shared__ int packed[CHUNK];   // 16 KB
    __shared__ int gpos[CHUNK];     // 16 KB

    int t = threadIdx.x;
    int chunkBase = blockIdx.x * CHUNK;

    // phase 1: local histogram
    for (int i = t; i < nbuck; i += 256) hist[i] = 0;
    __syncthreads();
#pragma unroll
    for (int k = 0; k < EPT; ++k) {
        int e = chunkBase + t + k * 256;
        if (e < E) atomicAdd(&hist[dst[e] >> BNODE_SHIFT], 1);
    }
    __syncthreads();

    // phase 2: exclusive scan of hist (2 items/thread covers <=512 buckets)
    int a0 = (2 * t < nbuck) ? hist[2 * t] : 0;
    int a1 = (2 * t + 1 < nbuck) ? hist[2 * t + 1] : 0;
    int s2 = a0 + a1;
    wsum[t] = s2;
    __syncthreads();
    for (int off = 1; off < 256; off <<= 1) {
        int x = (t >= off) ? wsum[t - off] : 0;
        __syncthreads();
        wsum[t] += x;
        __syncthreads();
    }
    int base = wsum[t] - s2;        // exclusive
    if (2 * t < nbuck)     bstart[2 * t] = base;
    if (2 * t + 1 < nbuck) bstart[2 * t + 1] = base + a0;
    if (t == 255) bstart[nbuck] = wsum[255];
    __syncthreads();

    // phase 2b: reserve global spans; init local cursors
    for (int b = t; b < nbuck; b += 256) {
        int cnt = bstart[b + 1] - bstart[b];
        gbase[b] = cnt ? (atomicAdd(&bcur[b * 16], cnt) - bstart[b]) : 0;
        cur[b] = bstart[b];
    }
    __syncthreads();

    // phase 3: place edges sorted into LDS; record final global position
    #pragma unroll
    for (int k = 0; k < EPT; ++k) {
        int e = chunkBase + t + k * 256;
        if (e < E) {
            int d = dst[e];
            int b = d >> BNODE_SHIFT;
            int pos = atomicAdd(&cur[b], 1);
            packed[pos] = src[e] | ((d & (BNODES - 1)) << 20);
            gpos[pos] = gbase[b] + pos;   // gbase pre-biased by -bstart[b]
        }
    }
    __syncthreads();

    // phase 4: flat parallel flush (coalesced LDS read; runs are contiguous globally)
    int nloc = bstart[nbuck];
    for (int j = t; j < nloc; j += 256)
        pairs4[gpos[j]] = packed[j];
}

// ---------------- exact CSR within each bucket (LDS atomics) ----------------
__global__ void bucket_build(const int* __restrict__ pairs4, const int* __restrict__ boff,
                             int* __restrict__ col, int* __restrict__ rowstart,
                             float* __restrict__ dinv, int N) {
    __shared__ int hist[BNODES];
    __shared__ int cur[BNODES];
    int b = blockIdx.x;
    int lo = boff[b], hi = boff[b + 1];
    int node0 = b << BNODE_SHIFT;
    int tid = threadIdx.x;
    hist[tid] = 0;
    __syncthreads();
    for (int e = lo + tid; e < hi; e += 256)
        atomicAdd(&hist[(pairs4[e] >> 20) & (BNODES - 1)], 1);
    __syncthreads();
    int v = hist[tid];
    cur[tid] = v;
    __syncthreads();
    for (int off = 1; off < BNODES; off <<= 1) {
        int x = (tid >= off) ? cur[tid - off] : 0;
        __syncthreads();
        cur[tid] += x;
        __syncthreads();
    }
    {
        int ex = cur[tid] - v;    // exclusive
        int node = node0 + tid;
        if (node < N) {
            rowstart[node] = lo + ex;
            dinv[node] = rsqrtf((float)(v + 1));   // +1 self-loop
        }
        cur[tid] = ex;            // local cursor
    }
    __syncthreads();
    for (int e = lo + tid; e < hi; e += 256) {
        int pr = pairs4[e];
        int p = atomicAdd(&cur[(pr >> 20) & (BNODES - 1)], 1);
        col[lo + p] = pr & 0xFFFFF;
    }
}

// ---------------- graph boundaries from sorted batch (no atomics) ----------------
__global__ void graph_bounds(const int* __restrict__ batch, int* __restrict__ nodestart,
                             int N, int G) {
    int i = blockIdx.x * blockDim.x + threadIdx.x;
    if (i >= N) return;
    int b = batch[i];
    int bp = (i == 0) ? -1 : batch[i - 1];
    for (int g = bp + 1; g <= b; ++g) nodestart[g] = i;
    if (i == N - 1) nodestart[G] = N;
}

// ---------------- segmented mean pool: one block per graph ----------------
__global__ void pool_mean(const float* __restrict__ h, const int* __restrict__ nodestart,
                          float* __restrict__ pooled, int G) {
    int g = blockIdx.x;
    int lo = nodestart[g], hi = nodestart[g + 1];
    int f = threadIdx.x & 63, w = threadIdx.x >> 6;
    float acc = 0.f;
    for (int n = lo + w; n < hi; n += 4) acc += h[(size_t)n * H + f];
    __shared__ float red[4][64];
    red[w][f] = acc;
    __syncthreads();
    if (w == 0) {
        float s = red[0][f] + red[1][f] + red[2][f] + red[3][f];
        float c = (float)(hi - lo);
        pooled[g * H + f] = s / fmaxf(c, 1.f);
    }
}

// ---------------- prep: pad x to 16 bf16/row (32B), pre-scaled by dinv ----------------
__global__ void prep_xb(const float* __restrict__ x, const float* __restrict__ dinv,
                        ushort* __restrict__ xb, int N) {
    int i = blockIdx.x * blockDim.x + threadIdx.x;
    if (i >= N * 16) return;
    int n = i >> 4, k = i & 15;
    xb[i] = (k < 9) ? f2b(x[n * 9 + k] * dinv[n]) : (ushort)0;
}

// ---------------- conv1 fused: agg = dinv_i*(sum xb[src] + xb[i]); out = relu(agg@W1+b1)
__global__ void conv1_fused(const ushort* __restrict__ xb, const float* __restrict__ dinv,
                            const int* __restrict__ rowstart,
                            const int* __restrict__ col, const float* __restrict__ W1,
                            const float* __restrict__ b1, float* __restrict__ out, int N) {
    int gtid = blockIdx.x * blockDim.x + threadIdx.x;
    int i = RFL(gtid >> 6);
    int lane = threadIdx.x & 63;
    int f16 = lane & 15, grp = lane >> 4;
    if (i >= N) return;
    float di = dinv[i];
    float sv = b2f(xb[(size_t)i * 16 + f16]);   // self (already dinv_i-scaled)
    float acc = 0.f;
    int s = rowstart[i], e = rowstart[i + 1];
    for (int base = s; base < e; base += 64) {
        int cnt = e - base;
        if (cnt > 64) cnt = 64;
        int idx = 0;
        if (lane < cnt) idx = col[base + lane];
        for (int j = 0; j < cnt; j += 8) {
            int j0 = j + grp, j1 = j + 4 + grp;
            int s0 = __shfl(idx, j0);
            int s1 = __shfl(idx, j1 & 63);
            float v0 = (j0 < cnt) ? b2f(xb[(size_t)s0 * 16 + f16]) : 0.f;
            float v1 = (j1 < cnt) ? b2f(xb[(size_t)s1 * 16 + f16]) : 0.f;
            acc += v0 + v1;
        }
    }
    // reduce 4 edge-groups
    acc += __shfl_xor(acc, 16);
    acc += __shfl_xor(acc, 32);
    float aggf = di * (acc + sv);            // lane k (k<9) holds agg[k]

    float o = b1[lane];
#pragma unroll
    for (int k = 0; k < 9; ++k) {
        float ak = __shfl(aggf, k);
        o = fmaf(ak, W1[k * H + lane], o);
    }
    out[(size_t)i * H + lane] = fmaxf(o, 0.f);
}

// ---------------- linear: N x 64 @ 64 x 64 (16 nodes/block), scaled, planar bf16 out ----------------
__global__ void lin_h(const float* __restrict__ h, const float* __restrict__ W,
                      const float* __restrict__ dinv,
                      ushort* __restrict__ out0, ushort* __restrict__ out1, int N) {
    __shared__ float Ws[H * H];     // 16 KB
    __shared__ float hs[16 * H];    // 4 KB
    int tid = threadIdx.x;
    int node0 = blockIdx.x * 16;
    for (int idx = tid; idx < H * H; idx += 256) Ws[idx] = W[idx];
    for (int idx = tid; idx < 16 * H; idx += 256) {
        int n = node0 + (idx >> 6);
        hs[idx] = (n < N) ? h[n * H + (idx & 63)] : 0.f;
    }
    __syncthreads();
    int nlb = tid >> 6, f = tid & 63;
    float a0 = 0.f, a1 = 0.f, a2 = 0.f, a3 = 0.f;
#pragma unroll 8
    for (int k = 0; k < H; ++k) {
        float w = Ws[k * H + f];
        a0 += hs[(nlb) * H + k] * w;
        a1 += hs[(nlb + 4) * H + k] * w;
        a2 += hs[(nlb + 8) * H + k] * w;
        a3 += hs[(nlb + 12) * H + k] * w;
    }
    ushort* op = (f < 32) ? out0 : out1;
    int fo = f & 31;
    int n;
    n = node0 + nlb;      if (n < N) op[(size_t)n * 32 + fo] = f2b(a0 * dinv[n]);
    n = node0 + nlb + 4;  if (n < N) op[(size_t)n * 32 + fo] = f2b(a1 * dinv[n]);
    n = node0 + nlb + 8;  if (n < N) op[(size_t)n * 32 + fo] = f2b(a2 * dinv[n]);
    n = node0 + nlb + 12; if (n < N) op[(size_t)n * 32 + fo] = f2b(a3 * dinv[n]);
}

// ---------------- aggregate half-plane (bf16, 2 edges/load) ----------------
// hp = 6.4MB plane of 32 features/node (64B rows -> one cache line each).
// lane&31 = feature, lane>>5 = edge parity; shfl_xor(32) combines parities.
template <int HALF>
__global__ void aggregate_h(const ushort* __restrict__ hp, const float* __restrict__ dinv,
                            const int* __restrict__ rowstart,
                            const int* __restrict__ col, const float* __restrict__ bias,
                            float* __restrict__ out, int N) {
    int gtid = blockIdx.x * blockDim.x + threadIdx.x;
    int i = RFL(gtid >> 6);     // node = wave (uniform, SGPR)
    int lane = threadIdx.x & 63;
    int f = lane & 31, pr = lane >> 5;
    if (i >= N) return;
    float self = b2f(hp[(size_t)i * 32 + f]);
    float acc = 0.f;
    int s = rowstart[i], e = rowstart[i + 1];
    int p = s;
    for (; p + 16 <= e; p += 16) {
        int a0 = RFL(col[p + 0]),  a1 = RFL(col[p + 1]);
        int a2 = RFL(col[p + 2]),  a3 = RFL(col[p + 3]);
        int a4 = RFL(col[p + 4]),  a5 = RFL(col[p + 5]);
        int a6 = RFL(col[p + 6]),  a7 = RFL(col[p + 7]);
        int a8 = RFL(col[p + 8]),  a9 = RFL(col[p + 9]);
        int aA = RFL(col[p + 10]), aB = RFL(col[p + 11]);
        int aC = RFL(col[p + 12]), aD = RFL(col[p + 13]);
        int aE = RFL(col[p + 14]), aF = RFL(col[p + 15]);
        int s0 = pr ? a1 : a0;
        int s1 = pr ? a3 : a2;
        int s2 = pr ? a5 : a4;
        int s3 = pr ? a7 : a6;
        int s4 = pr ? a9 : a8;
        int s5 = pr ? aB : aA;
        int s6 = pr ? aD : aC;
        int s7 = pr ? aF : aE;
        float v0 = b2f(hp[(size_t)s0 * 32 + f]);
        float v1 = b2f(hp[(size_t)s1 * 32 + f]);
        float v2 = b2f(hp[(size_t)s2 * 32 + f]);
        float v3 = b2f(hp[(size_t)s3 * 32 + f]);
        float v4 = b2f(hp[(size_t)s4 * 32 + f]);
        float v5 = b2f(hp[(size_t)s5 * 32 + f]);
        float v6 = b2f(hp[(size_t)s6 * 32 + f]);
        float v7 = b2f(hp[(size_t)s7 * 32 + f]);
        acc += ((v0 + v1) + (v2 + v3)) + ((v4 + v5) + (v6 + v7));
    }
    for (; p + 2 <= e; p += 2) {
        int a0 = RFL(col[p]), a1 = RFL(col[p + 1]);
        int s0 = pr ? a1 : a0;
        acc += b2f(hp[(size_t)s0 * 32 + f]);
    }
    if (p < e) {
        int a0 = RFL(col[p]);
        float v = b2f(hp[(size_t)a0 * 32 + f]);
        if (pr == 0) acc += v;
    }
    acc += __shfl_xor(acc, 32);
    if (pr == 0) {
        float r = fmaxf(bias[HALF * 32 + f] + dinv[i] * (acc + self), 0.f);
        __builtin_nontemporal_store(r, &out[(size_t)i * H + HALF * 32 + f]);
    }
}

// ---------------- final MLP: one wave per graph, shfl-based ----------------
__global__ void mlp(const float* __restrict__ pooled, const float* __restrict__ u,
                    const float* __restrict__ A1, const float* __restrict__ c1,
                    const float* __restrict__ A2, const float* __restrict__ c2,
                    const float* __restrict__ A3, const float* __restrict__ c3,
                    const float* __restrict__ A4, const float* __restrict__ c4,
                    const float* __restrict__ A5, const float* __restrict__ c5,
                    float* __restrict__ out, int G) {
    int wid = (blockIdx.x * blockDim.x + threadIdx.x) >> 6;  // wave = graph
    int lane = threadIdx.x & 63;
    if (wid >= G) return;
    int g = wid;

    float zreg = pooled[g * H + lane];
    float u0 = u[g * 4 + 0], u1 = u[g * 4 + 1], u2 = u[g * 4 + 2], u3 = u[g * 4 + 3];

    // layer 1: 68 -> 50
    float acc = (lane < 50) ? c1[lane] : 0.f;
#pragma unroll
    for (int k = 0; k < 64; ++k) {
        float zk = __shfl(zreg, k);
        float w = (lane < 50) ? A1[k * 50 + lane] : 0.f;
        acc = fmaf(zk, w, acc);
    }
    {
        float w;
        w = (lane < 50) ? A1[64 * 50 + lane] : 0.f; acc = fmaf(u0, w, acc);
        w = (lane < 50) ? A1[65 * 50 + lane] : 0.f; acc = fmaf(u1, w, acc);
        w = (lane < 50) ? A1[66 * 50 + lane] : 0.f; acc = fmaf(u2, w, acc);
        w = (lane < 50) ? A1[67 * 50 + lane] : 0.f; acc = fmaf(u3, w, acc);
    }
    float z1v = fmaxf(acc, 0.f);

    // layer 2: 50 -> 30
    acc = (lane < 30) ? c2[lane] : 0.f;
#pragma unroll
    for (int k = 0; k < 50; ++k) {
        float zk = __shfl(z1v, k);
        float w = (lane < 30) ? A2[k * 30 + lane] : 0.f;
        acc = fmaf(zk, w, acc);
    }
    float z2v = fmaxf(acc, 0.f);

    // layer 3: 30 -> 20
    acc = (lane < 20) ? c3[lane] : 0.f;
#pragma unroll
    for (int k = 0; k < 30; ++k) {
        float zk = __shfl(z2v, k);
        float w = (lane < 20) ? A3[k * 20 + lane] : 0.f;
        acc = fmaf(zk, w, acc);
    }
    float z3v = fmaxf(acc, 0.f);

    // layer 4: 20 -> 5
    acc = (lane < 5) ? c4[lane] : 0.f;
#pragma unroll
    for (int k = 0; k < 20; ++k) {
        float zk = __shfl(z3v, k);
        float w = (lane < 5) ? A4[k * 5 + lane] : 0.f;
        acc = fmaf(zk, w, acc);
    }
    float z4v = fmaxf(acc, 0.f);

    // layer 5: 5 -> 1
    acc = c5[0];
#pragma unroll
    for (int k = 0; k < 5; ++k) {
        float zk = __shfl(z4v, k);
        acc = fmaf(zk, A5[k], acc);
    }
    if (lane == 0) out[g] = fmaxf(acc, 0.f);
}

extern "C" void kernel_launch(void* const* d_in, const int* in_sizes, int n_in,
                              void* d_out, int out_size, void* d_ws, size_t ws_size,
                              hipStream_t stream) {
    const float* x     = (const float*)d_in[0];
    const int*   edge  = (const int*)d_in[1];
    const int*   batch = (const int*)d_in[2];
    const float* u     = (const float*)d_in[3];
    const float* W1 = (const float*)d_in[4];  const float* b1 = (const float*)d_in[5];
    const float* W2 = (const float*)d_in[6];  const float* b2 = (const float*)d_in[7];
    const float* W3 = (const float*)d_in[8];  const float* b3 = (const float*)d_in[9];
    const float* A1 = (const float*)d_in[10]; const float* c1 = (const float*)d_in[11];
    const float* A2 = (const float*)d_in[12]; const float* c2 = (const float*)d_in[13];
    const float* A3 = (const float*)d_in[14]; const float* c3 = (const float*)d_in[15];
    const float* A4 = (const float*)d_in[16]; const float* c4 = (const float*)d_in[17];
    const float* A5 = (const float*)d_in[18]; const float* c5 = (const float*)d_in[19];

    const int N = in_sizes[2];          // 100000
    const int E = in_sizes[1] / 2;      // 3200000
    const int G = in_sizes[3] / 4;      // 256
    const int* src = edge;
    const int* dst = edge + E;
    const int nbuck = (N + BNODES - 1) >> BNODE_SHIFT;   // 391

    // ---- workspace layout (pairs4 aliases hb0+hb1: pairs4 dead before lin_h writes) ----
    char* ws = (char*)d_ws;
    size_t off = 0;
    auto alloc = [&](size_t bytes) -> void* {
        void* p = ws + off;
        off = (off + bytes + 255) & ~(size_t)255;
        return p;
    };
    ushort* hb0      = (ushort*)alloc((size_t)N * 32 * 2);  // plane 0 (features 0-31)
    ushort* hb1      = (ushort*)alloc((size_t)N * 32 * 2);  // plane 1 (features 32-63)
    float*  h        = (float*)alloc((size_t)N * H * 4);
    int*    col      = (int*)alloc((size_t)E * 4);
    ushort* xb       = (ushort*)alloc((size_t)N * 16 * 2);
    int*    rowstart = (int*)alloc((size_t)(N + 1) * 4);
    float*  dinv     = (float*)alloc((size_t)N * 4);
    int*    bcounts  = (int*)alloc((size_t)nbuck * 4);
    int*    boff     = (int*)alloc((size_t)(nbuck + 1) * 4);
    int*    bcur     = (int*)alloc((size_t)nbuck * 64);    // 64B-padded cursors
    int*    nodestart= (int*)alloc((size_t)(G + 1) * 4);
    float*  pooled   = (float*)alloc((size_t)G * H * 4);
    int*    pairs4   = (int*)hb0;    // E*4 = 12.8MB == hb0+hb1 (contiguous)

    const int nbN   = (N + 255) / 256;
    const int nbAgg = (N + 3) / 4;       // 4 waves/block, wave per node
    const int nchunks = (E + CHUNK - 1) / CHUNK;   // 782

    // ---- CSR build via block-local LDS sort ----
    zero_i32<<<(nbuck + 255) / 256, 256, 0, stream>>>(bcounts, nbuck);
    bucket_hist<<<256, 256, 0, stream>>>(dst, E, bcounts, nbuck);
    bucket_scan<<<1, 1024, 0, stream>>>(bcounts, boff, bcur, rowstart, nbuck, E, N);
    edge_sort_scatter<<<nchunks, 256, 0, stream>>>(src, dst, E, nbuck, bcur, pairs4);
    bucket_build<<<nbuck, 256, 0, stream>>>(pairs4, boff, col, rowstart, dinv, N);
    graph_bounds<<<nbN, 256, 0, stream>>>(batch, nodestart, N, G);

    // ---- conv1 (fused: aggregate 9-wide raw bf16 x, then W1) ----
    prep_xb<<<(N * 16 + 255) / 256, 256, 0, stream>>>(x, dinv, xb, N);
    conv1_fused<<<nbAgg, 256, 0, stream>>>(xb, dinv, rowstart, col, W1, b1, h, N);
    // ---- conv2 ----
    lin_h<<<(N + 15) / 16, 256, 0, stream>>>(h, W2, dinv, hb0, hb1, N);
    aggregate_h<0><<<nbAgg, 256, 0, stream>>>(hb0, dinv, rowstart, col, b2, h, N);
    aggregate_h<1><<<nbAgg, 256, 0, stream>>>(hb1, dinv, rowstart, col, b2, h, N);
    // ---- conv3 ----
    lin_h<<<(N + 15) / 16, 256, 0, stream>>>(h, W3, dinv, hb0, hb1, N);
    aggregate_h<0><<<nbAgg, 256, 0, stream>>>(hb0, dinv, rowstart, col, b3, h, N);
    aggregate_h<1><<<nbAgg, 256, 0, stream>>>(hb1, dinv, rowstart, col, b3, h, N);

    // ---- mean pool + final MLP ----
    pool_mean<<<G, 256, 0, stream>>>(h, nodestart, pooled, G);
    mlp<<<(G * 64 + 255) / 256, 256, 0, stream>>>(pooled, u, A1, c1, A2, c2, A3, c3,
                                                  A4, c4, A5, c5, (float*)d_out, G);
}